// Round 2
// 1058.739 us; speedup vs baseline: 1.0339x; 1.0339x over previous
//
#include <hip/hip_runtime.h>
#include <math.h>

#define B_SZ   8192
#define FEATN  1024
#define DCOL   4096
#define NS     5
#define NN     7      // tree nodes
#define HIDN   64
#define NTREE  448    // 7*64
#define NDIR   256
#define NTOT   704

// R3: R2 resubmit. R2 failed to COMPILE: __builtin_nontemporal_load/store
// rejects HIP_vector_type<float,4>* — needs a native clang vector type.
// Fixed via ext_vector_type(4) alias in htg_combine; everything else identical.
//
// R2 rationale (from R1 rocprof): all 3 kernels in [259,418]us (top-5 all fills
// at ~418; sum=1094). htg_gates (arith floor ~30us) was >=259us -> 64-wide shfl
// reduction chains at 1 wave/block are pathological. Fix: LN/gelu/node-softmax/
// direct-projection fused into GEMM epilogue via 16-lane reductions (row's 64
// cols live in 16 contiguous lanes); GEMM writes 27 floats/row, not 704.

#define BM 128
#define BN 64
#define BK 16
#define LDA 132   // pad: no bank conflict on transposed scatter
#define LDB 68

typedef float f32x4_t __attribute__((ext_vector_type(4)));

__device__ inline float gelu_exact(float x) {
    return 0.5f * x * (1.f + erff(x * 0.70710678118654752f));
}

__global__ __launch_bounds__(256) void htg_gemm_fused(
    const float* __restrict__ A, const float* __restrict__ tw1,
    const float* __restrict__ dw1,
    const float* __restrict__ tb1, const float* __restrict__ tg,
    const float* __restrict__ tbn, const float* __restrict__ tw2,
    const float* __restrict__ tb2,
    const float* __restrict__ db1, const float* __restrict__ dw2,
    float* __restrict__ np_out, float* __restrict__ dpart_out)
{
    __shared__ float As[BK * LDA];
    __shared__ float Bs[BK * LDB];
    const int tid = threadIdx.x;
    const int bm0 = blockIdx.x * BM;
    const int bn0 = blockIdx.y * BN;
    // whole 64-wide N tile is either tree weights or direct weights (448 = 7*64)
    const float* Wsrc = (bn0 < NTREE) ? (tw1 + (size_t)bn0 * FEATN)
                                      : (dw1 + (size_t)(bn0 - NTREE) * FEATN);
    const int ty  = tid >> 4;   // 0..15 -> rows ty*8..+7
    const int tx  = tid & 15;   // 0..15 -> cols tx*4..+3
    const int lr  = tid >> 2;   // 0..63 load row
    const int lc4 = tid & 3;    // 0..3  load col (float4 granularity)

    float acc[8][4];
#pragma unroll
    for (int i = 0; i < 8; ++i)
#pragma unroll
        for (int j = 0; j < 4; ++j) acc[i][j] = 0.f;

    float4 aR0, aR1, bR;
    {
        const float* Ap = A + (size_t)(bm0 + lr) * FEATN + lc4 * 4;
        aR0 = *(const float4*)(Ap);
        aR1 = *(const float4*)(Ap + (size_t)64 * FEATN);
        bR  = *(const float4*)(Wsrc + (size_t)lr * FEATN + lc4 * 4);
    }
    const int KT = FEATN / BK;
    for (int kt = 0; kt < KT; ++kt) {
        {   // scatter regs -> LDS transposed [k][m]
            float av0[4] = {aR0.x, aR0.y, aR0.z, aR0.w};
            float av1[4] = {aR1.x, aR1.y, aR1.z, aR1.w};
            float bv[4]  = {bR.x,  bR.y,  bR.z,  bR.w};
#pragma unroll
            for (int j = 0; j < 4; ++j) {
                As[(lc4 * 4 + j) * LDA + lr]      = av0[j];
                As[(lc4 * 4 + j) * LDA + lr + 64] = av1[j];
                Bs[(lc4 * 4 + j) * LDB + lr]      = bv[j];
            }
        }
        __syncthreads();
        if (kt + 1 < KT) {  // prefetch next tile into regs (hide under compute)
            const int k0 = (kt + 1) * BK;
            const float* Ap = A + (size_t)(bm0 + lr) * FEATN + k0 + lc4 * 4;
            aR0 = *(const float4*)(Ap);
            aR1 = *(const float4*)(Ap + (size_t)64 * FEATN);
            bR  = *(const float4*)(Wsrc + (size_t)lr * FEATN + k0 + lc4 * 4);
        }
#pragma unroll
        for (int kk = 0; kk < BK; ++kk) {
            float4 a0 = *(const float4*)&As[kk * LDA + ty * 8];
            float4 a1 = *(const float4*)&As[kk * LDA + ty * 8 + 4];
            float4 b  = *(const float4*)&Bs[kk * LDB + tx * 4];
            float av[8] = {a0.x, a0.y, a0.z, a0.w, a1.x, a1.y, a1.z, a1.w};
            float bv[4] = {b.x, b.y, b.z, b.w};
#pragma unroll
            for (int i = 0; i < 8; ++i)
#pragma unroll
                for (int j = 0; j < 4; ++j)
                    acc[i][j] = fmaf(av[i], bv[j], acc[i][j]);
        }
        __syncthreads();
    }

    // ---------------- fused epilogue ----------------
    // Row r = bm0+ty*8+i has its 64 cols in the 16 contiguous lanes (ty&3)*16..+15
    // of wave ty>>2 -> 16-lane shfl_xor reductions (masks 8,4,2,1) stay in-group.
    const int ib = blockIdx.y;
    if (ib < NN) {
        const int n = ib;
        const int col = tx * 4;
        const float4 tb1v = *(const float4*)&tb1[n * HIDN + col];
        const float4 tgv  = *(const float4*)&tg [n * HIDN + col];
        const float4 tbnv = *(const float4*)&tbn[n * HIDN + col];
        const float4 w2av = *(const float4*)&tw2[(n * 2 + 0) * HIDN + col];
        const float4 w2bv = *(const float4*)&tw2[(n * 2 + 1) * HIDN + col];
        const float b2a = tb2[n * 2], b2b = tb2[n * 2 + 1];
        const float tb1a[4] = {tb1v.x, tb1v.y, tb1v.z, tb1v.w};
        const float tga[4]  = {tgv.x,  tgv.y,  tgv.z,  tgv.w};
        const float tbna[4] = {tbnv.x, tbnv.y, tbnv.z, tbnv.w};
        const float w2aa[4] = {w2av.x, w2av.y, w2av.z, w2av.w};
        const float w2ba[4] = {w2bv.x, w2bv.y, w2bv.z, w2bv.w};
#pragma unroll
        for (int i = 0; i < 8; ++i) {
            float x[4]; float s = 0.f, sq = 0.f;
#pragma unroll
            for (int j = 0; j < 4; ++j) {
                x[j] = acc[i][j] + tb1a[j];
                s += x[j];
                sq = fmaf(x[j], x[j], sq);
            }
#pragma unroll
            for (int o = 8; o > 0; o >>= 1) {
                s  += __shfl_xor(s,  o, 64);
                sq += __shfl_xor(sq, o, 64);
            }
            const float mu  = s * (1.f / 64.f);
            const float var = sq * (1.f / 64.f) - mu * mu;
            const float rs  = rsqrtf(var + 1e-5f);
            float o0 = 0.f, o1 = 0.f;
#pragma unroll
            for (int j = 0; j < 4; ++j) {
                const float g = gelu_exact((x[j] - mu) * rs * tga[j] + tbna[j]);
                o0 = fmaf(g, w2aa[j], o0);
                o1 = fmaf(g, w2ba[j], o1);
            }
#pragma unroll
            for (int o = 8; o > 0; o >>= 1) {
                o0 += __shfl_xor(o0, o, 64);
                o1 += __shfl_xor(o1, o, 64);
            }
            o0 += b2a; o1 += b2b;
            // softmax([o0,o1]/0.5): p0 = 1/(1+exp(2*(o1-o0)))
            const float p0 = 1.f / (1.f + expf(2.f * (o1 - o0)));
            if (tx == 0) np_out[(size_t)(bm0 + ty * 8 + i) * NN + n] = p0;
        }
    } else {
        const int cb  = ib - NN;            // 0..3 direct col-block
        const int col = cb * HIDN + tx * 4; // 0..255
        const float4 dbv = *(const float4*)&db1[col];
        const float dba[4] = {dbv.x, dbv.y, dbv.z, dbv.w};
        float w2[NS][4];
#pragma unroll
        for (int s5 = 0; s5 < NS; ++s5) {
            const float4 v = *(const float4*)&dw2[s5 * NDIR + col];
            w2[s5][0] = v.x; w2[s5][1] = v.y; w2[s5][2] = v.z; w2[s5][3] = v.w;
        }
#pragma unroll
        for (int i = 0; i < 8; ++i) {
            float part[NS] = {0.f, 0.f, 0.f, 0.f, 0.f};
#pragma unroll
            for (int j = 0; j < 4; ++j) {
                const float d = gelu_exact(acc[i][j] + dba[j]);
#pragma unroll
                for (int s5 = 0; s5 < NS; ++s5) part[s5] = fmaf(d, w2[s5][j], part[s5]);
            }
#pragma unroll
            for (int o = 8; o > 0; o >>= 1)
#pragma unroll
                for (int s5 = 0; s5 < NS; ++s5) part[s5] += __shfl_xor(part[s5], o, 64);
            if (tx == 0) {
                const size_t r = bm0 + ty * 8 + i;
#pragma unroll
                for (int s5 = 0; s5 < NS; ++s5)
                    dpart_out[r * 20 + cb * NS + s5] = part[s5];
            }
        }
    }
}

// ---------------- gates-lite: one thread per batch row (pure scalar, ~300 flops) ----------------
__device__ inline void softmax5(float* v) {
    float m = v[0];
#pragma unroll
    for (int s = 1; s < NS; ++s) m = fmaxf(m, v[s]);
    float sum = 0.f;
#pragma unroll
    for (int s = 0; s < NS; ++s) { v[s] = expf(v[s] - m); sum += v[s]; }
    const float inv = 1.f / sum;
#pragma unroll
    for (int s = 0; s < NS; ++s) v[s] *= inv;
}

__global__ __launch_bounds__(256) void htg_gates_lite(
    const float* __restrict__ np, const float* __restrict__ dpart,
    const float* __restrict__ lw1, const float* __restrict__ lb1,
    const float* __restrict__ lw2, const float* __restrict__ lb2,
    const float* __restrict__ db2, const float* __restrict__ cw,
    float* __restrict__ gates_out)
{
    const int b = blockIdx.x * 256 + threadIdx.x;  // grid 32x256 = 8192 exact
    float np0[NN], np1[NN];
#pragma unroll
    for (int n = 0; n < NN; ++n) {
        np0[n] = np[(size_t)b * NN + n];
        np1[n] = 1.f - np0[n];
    }
    float lp[8];
#pragma unroll
    for (int leaf = 0; leaf < 8; ++leaf) {
        const int c0 = (leaf >> 2) & 1, c1 = (leaf >> 1) & 1, c2 = leaf & 1;
        const float v0 = c0 ? np1[0] : np0[0];
        const float v1 = c1 ? np1[1 + c0] : np0[1 + c0];
        const float v2 = c2 ? np1[3 + 2 * c0 + c1] : np0[3 + 2 * c0 + c1];
        lp[leaf] = v0 * v1 * v2;
    }
    float t[10];
#pragma unroll
    for (int j = 0; j < 10; ++j) {
        float a = lb1[j];
#pragma unroll
        for (int leaf = 0; leaf < 8; ++leaf) a = fmaf(lp[leaf], lw1[j * 8 + leaf], a);
        t[j] = gelu_exact(a);
    }
    float tgt[NS];
#pragma unroll
    for (int s = 0; s < NS; ++s) {
        float a = lb2[s];
#pragma unroll
        for (int j = 0; j < 10; ++j) a = fmaf(t[j], lw2[s * 10 + j], a);
        tgt[s] = a;
    }
    softmax5(tgt);
    float dgt[NS];
#pragma unroll
    for (int s = 0; s < NS; ++s) {
        float a = db2[s];
#pragma unroll
        for (int cb = 0; cb < 4; ++cb) a += dpart[(size_t)b * 20 + cb * NS + s];
        dgt[s] = a;
    }
    softmax5(dgt);
    const float w = 1.f / (1.f + expf(-cw[0]));
    float g5[NS]; float sum = 0.f;
#pragma unroll
    for (int s = 0; s < NS; ++s) {
        g5[s] = fmaf(w, tgt[s] - dgt[s], dgt[s]);  // w*tgt + (1-w)*dgt
        sum += g5[s];
    }
    const float inv = 1.f / sum;
#pragma unroll
    for (int s = 0; s < NS; ++s) gates_out[(size_t)b * NS + s] = g5[s] * inv;
}

// ---------------- combine: out[b][d] = sum_s gates[b][s] * logits[s][b][d] ----------------
// 1 block per row: 16KB sequential run per stream (DRAM page locality) vs 4KB before.
// logits are stream-once (671MB > L3) -> nontemporal; out is write-once -> nontemporal.
// Nontemporal builtins need native clang vectors (ext_vector_type), not float4.
__global__ __launch_bounds__(256) void htg_combine(
    const float* __restrict__ logits, const float* __restrict__ gates,
    float* __restrict__ out)
{
    const int b = blockIdx.x;
    float g[NS];
#pragma unroll
    for (int s = 0; s < NS; ++s) g[s] = gates[(size_t)b * NS + s];  // block-uniform
    const f32x4_t* lp = (const f32x4_t*)logits;
    f32x4_t* op = (f32x4_t*)out;
    const size_t rowbase = (size_t)b * (DCOL / 4);
#pragma unroll
    for (int u = 0; u < 4; ++u) {
        const size_t idx = rowbase + u * 256 + threadIdx.x;
        f32x4_t a = (f32x4_t)(0.f);
#pragma unroll
        for (int s = 0; s < NS; ++s) {
            const f32x4_t v = __builtin_nontemporal_load(&lp[(size_t)s * B_SZ * (DCOL / 4) + idx]);
            a.x = fmaf(g[s], v.x, a.x);
            a.y = fmaf(g[s], v.y, a.y);
            a.z = fmaf(g[s], v.z, a.z);
            a.w = fmaf(g[s], v.w, a.w);
        }
        __builtin_nontemporal_store(a, &op[idx]);
    }
}

extern "C" void kernel_launch(void* const* d_in, const int* in_sizes, int n_in,
                              void* d_out, int out_size, void* d_ws, size_t ws_size,
                              hipStream_t stream) {
    const float* features = (const float*)d_in[0];
    const float* logits   = (const float*)d_in[1];
    const float* tw1      = (const float*)d_in[2];
    const float* tb1      = (const float*)d_in[3];
    const float* tg       = (const float*)d_in[4];
    const float* tbn      = (const float*)d_in[5];
    const float* tw2      = (const float*)d_in[6];
    const float* tb2      = (const float*)d_in[7];
    const float* lw1      = (const float*)d_in[8];
    const float* lb1      = (const float*)d_in[9];
    const float* lw2      = (const float*)d_in[10];
    const float* lb2      = (const float*)d_in[11];
    const float* dw1      = (const float*)d_in[12];
    const float* db1      = (const float*)d_in[13];
    const float* dw2      = (const float*)d_in[14];
    const float* db2      = (const float*)d_in[15];
    const float* cw       = (const float*)d_in[16];

    float* out   = (float*)d_out;
    float* gates = out + (size_t)B_SZ * DCOL;  // tail of d_out (output 1)

    // scratch: np[B][7] + dpart[B][4][5] = 27 floats/row = 884KB.
    // Prefer d_ws; fall back to front of d_out (combine overwrites it last,
    // after gates_lite has consumed the scratch -> stream-ordered safe).
    const size_t scratch_bytes = (size_t)B_SZ * 27 * sizeof(float);
    float* scratch   = (ws_size >= scratch_bytes) ? (float*)d_ws : (float*)d_out;
    float* np_buf    = scratch;
    float* dpart_buf = scratch + (size_t)B_SZ * NN;

    dim3 gemm_grid(B_SZ / BM, NTOT / BN);  // 64 x 11
    htg_gemm_fused<<<gemm_grid, 256, 0, stream>>>(features, tw1, dw1,
                                                  tb1, tg, tbn, tw2, tb2,
                                                  db1, dw2, np_buf, dpart_buf);

    htg_gates_lite<<<B_SZ / 256, 256, 0, stream>>>(np_buf, dpart_buf,
                                                   lw1, lb1, lw2, lb2, db2, cw,
                                                   gates);

    htg_combine<<<B_SZ, 256, 0, stream>>>(logits, gates, out);
}

// Round 3
// 1042.448 us; speedup vs baseline: 1.0500x; 1.0156x over previous
//
#include <hip/hip_runtime.h>
#include <math.h>

#define B_SZ   8192
#define FEATN  1024
#define DCOL   4096
#define NS     5
#define NN     7      // tree nodes
#define HIDN   64
#define NTREE  448    // 7*64
#define NDIR   256
#define NTOT   704

// R4: MFMA GEMM via bf16 hi/lo split (3-pass, tf32-class precision).
// Attribution model after R3: timed region = ~425us workspace re-poison fill +
// ~633us of our kernels (each <425, gates ~5 -> GEMM and combine each 200-420).
// GEMM moves from fp32 VALU (floor 75us, measured ~250-400) to matrix pipe:
// 3x11.8 GFLOP bf16 MFMA = 17us pipe time, L2-bound ~100us expected.
// Fragment layouts (learn_hip m89-verified): A lane holds row=lane&15,
// k=(lane>>4)*8+j (16B contiguous); B mirrors with col=lane&15 -> both operands
// load straight from global row-major bf16, NO LDS, NO barriers.
// C/D: col=lane&15, row=(lane>>4)*4+reg -> epilogue reductions = 16-lane shfl.

typedef float  f32x4_t  __attribute__((ext_vector_type(4)));
typedef short  bf16x8_t __attribute__((ext_vector_type(8)));
typedef unsigned short u16;

__device__ inline float gelu_exact(float x) {
    return 0.5f * x * (1.f + erff(x * 0.70710678118654752f));
}
__device__ inline u16 f32_to_bf16_rne(float x) {
    unsigned u = __float_as_uint(x);
    return (u16)((u + 0x7FFFu + ((u >> 16) & 1u)) >> 16);
}

// ---------------- conversion: fp32 -> (hi, lo) bf16 pair ----------------
// Ah/Al: [B_SZ][FEATN]; Wh/Wl: [NTOT][FEATN] = concat(tw1 448 rows, dw1 256 rows)
__global__ __launch_bounds__(256) void htg_convert(
    const float* __restrict__ feat, const float* __restrict__ tw1,
    const float* __restrict__ dw1,
    u16* __restrict__ Ah, u16* __restrict__ Al,
    u16* __restrict__ Wh, u16* __restrict__ Wl)
{
    const int NF4 = (B_SZ * FEATN) / 4;    // 2,097,152 float4s of features
    const int NT4 = (NTREE * FEATN) / 4;   // tw1 float4s
    const int NW4 = (NTOT * FEATN) / 4;    // all weight float4s
    const int total = NF4 + NW4;
    for (int i = blockIdx.x * 256 + threadIdx.x; i < total; i += gridDim.x * 256) {
        float4 v;
        u16 *hq, *lq; int o;
        if (i < NF4) {
            v = ((const float4*)feat)[i];
            hq = Ah; lq = Al; o = i * 4;
        } else {
            const int wi = i - NF4;
            v = (wi < NT4) ? ((const float4*)tw1)[wi] : ((const float4*)dw1)[wi - NT4];
            hq = Wh; lq = Wl; o = wi * 4;
        }
        const float xs[4] = {v.x, v.y, v.z, v.w};
        ushort4 hv, lv;
        u16 h[4], l[4];
#pragma unroll
        for (int j = 0; j < 4; ++j) {
            h[j] = f32_to_bf16_rne(xs[j]);
            const float fhi = __uint_as_float(((unsigned)h[j]) << 16);
            l[j] = f32_to_bf16_rne(xs[j] - fhi);
        }
        hv.x = h[0]; hv.y = h[1]; hv.z = h[2]; hv.w = h[3];
        lv.x = l[0]; lv.y = l[1]; lv.z = l[2]; lv.w = l[3];
        *(ushort4*)(hq + o) = hv;
        *(ushort4*)(lq + o) = lv;
    }
}

// ---------------- MFMA GEMM + fused epilogue ----------------
// Block: 256 threads = 4 waves; wave w covers rows bm0+w*32..+31 (2 M-tiles).
// BN=64 cols = 4 N-tiles = one tree node or one direct col-block.
// Grid (64, 11). No LDS, no barriers: fragments load direct from global (L2).
__global__ __launch_bounds__(256) void htg_gemm_mfma(
    const u16* __restrict__ Ah, const u16* __restrict__ Al,
    const u16* __restrict__ Wh, const u16* __restrict__ Wl,
    const float* __restrict__ tb1, const float* __restrict__ tg,
    const float* __restrict__ tbn, const float* __restrict__ tw2,
    const float* __restrict__ tb2,
    const float* __restrict__ db1, const float* __restrict__ dw2,
    float* __restrict__ np_out, float* __restrict__ dpart_out)
{
    const int tid  = threadIdx.x;
    const int wave = tid >> 6;
    const int lane = tid & 63;
    const int cidx = lane & 15;        // fragment row (A) / col (B,D)
    const int kgrp = (lane >> 4) * 8;  // fragment k-offset
    const int bm0  = blockIdx.x * 128;
    const int bn0  = blockIdx.y * 64;

    const size_t a0 = (size_t)(bm0 + wave * 32 + cidx) * FEATN;  // mt=0 row
    const size_t a1 = a0 + (size_t)16 * FEATN;                   // mt=1 row
    size_t woff[4];
#pragma unroll
    for (int n = 0; n < 4; ++n)
        woff[n] = (size_t)(bn0 + n * 16 + cidx) * FEATN;

    f32x4_t acc[2][4];
#pragma unroll
    for (int m = 0; m < 2; ++m)
#pragma unroll
        for (int n = 0; n < 4; ++n) acc[m][n] = (f32x4_t)(0.f);

#pragma unroll 2
    for (int k0 = 0; k0 < FEATN; k0 += 32) {
        const int ko = k0 + kgrp;
        const bf16x8_t a0h = *(const bf16x8_t*)(Ah + a0 + ko);
        const bf16x8_t a0l = *(const bf16x8_t*)(Al + a0 + ko);
        const bf16x8_t a1h = *(const bf16x8_t*)(Ah + a1 + ko);
        const bf16x8_t a1l = *(const bf16x8_t*)(Al + a1 + ko);
#pragma unroll
        for (int n = 0; n < 4; ++n) {
            const bf16x8_t wh = *(const bf16x8_t*)(Wh + woff[n] + ko);
            const bf16x8_t wl = *(const bf16x8_t*)(Wl + woff[n] + ko);
            acc[0][n] = __builtin_amdgcn_mfma_f32_16x16x32_bf16(a0l, wh, acc[0][n], 0, 0, 0);
            acc[0][n] = __builtin_amdgcn_mfma_f32_16x16x32_bf16(a0h, wl, acc[0][n], 0, 0, 0);
            acc[0][n] = __builtin_amdgcn_mfma_f32_16x16x32_bf16(a0h, wh, acc[0][n], 0, 0, 0);
            acc[1][n] = __builtin_amdgcn_mfma_f32_16x16x32_bf16(a1l, wh, acc[1][n], 0, 0, 0);
            acc[1][n] = __builtin_amdgcn_mfma_f32_16x16x32_bf16(a1h, wl, acc[1][n], 0, 0, 0);
            acc[1][n] = __builtin_amdgcn_mfma_f32_16x16x32_bf16(a1h, wh, acc[1][n], 0, 0, 0);
        }
    }

    // ---- fused epilogue. D layout: col = n*16 + cidx, row = (lane>>4)*4 + r.
    // A row's 64 cols live in one 16-lane group (lane>>4 fixed) across 4 n-tiles
    // -> reductions are shfl_xor masks 1,2,4,8 (stay within the group).
    const int ib = blockIdx.y;
    if (ib < NN) {
        const int n0 = ib;
        float tb1a[4], tga[4], tbna[4], w2aa[4], w2ba[4];
#pragma unroll
        for (int n = 0; n < 4; ++n) {
            const int col = n * 16 + cidx;
            tb1a[n] = tb1[n0 * HIDN + col];
            tga[n]  = tg [n0 * HIDN + col];
            tbna[n] = tbn[n0 * HIDN + col];
            w2aa[n] = tw2[(n0 * 2 + 0) * HIDN + col];
            w2ba[n] = tw2[(n0 * 2 + 1) * HIDN + col];
        }
        const float b2a = tb2[n0 * 2], b2b = tb2[n0 * 2 + 1];
#pragma unroll
        for (int mt = 0; mt < 2; ++mt) {
#pragma unroll
            for (int r = 0; r < 4; ++r) {
                float x[4]; float s = 0.f, sq = 0.f;
#pragma unroll
                for (int n = 0; n < 4; ++n) {
                    x[n] = acc[mt][n][r] + tb1a[n];
                    s += x[n];
                    sq = fmaf(x[n], x[n], sq);
                }
#pragma unroll
                for (int o = 8; o > 0; o >>= 1) {
                    s  += __shfl_xor(s,  o, 64);
                    sq += __shfl_xor(sq, o, 64);
                }
                const float mu  = s * (1.f / 64.f);
                const float var = sq * (1.f / 64.f) - mu * mu;
                const float rs  = rsqrtf(var + 1e-5f);
                float o0 = 0.f, o1 = 0.f;
#pragma unroll
                for (int n = 0; n < 4; ++n) {
                    const float g = gelu_exact((x[n] - mu) * rs * tga[n] + tbna[n]);
                    o0 = fmaf(g, w2aa[n], o0);
                    o1 = fmaf(g, w2ba[n], o1);
                }
#pragma unroll
                for (int o = 8; o > 0; o >>= 1) {
                    o0 += __shfl_xor(o0, o, 64);
                    o1 += __shfl_xor(o1, o, 64);
                }
                o0 += b2a; o1 += b2b;
                const float p0 = 1.f / (1.f + expf(2.f * (o1 - o0)));
                if (cidx == 0) {
                    const int row = bm0 + wave * 32 + mt * 16 + (lane >> 4) * 4 + r;
                    np_out[(size_t)row * NN + n0] = p0;
                }
            }
        }
    } else {
        const int cb = ib - NN;  // 0..3
        float dba[4], w2d[NS][4];
#pragma unroll
        for (int n = 0; n < 4; ++n) {
            const int col = cb * HIDN + n * 16 + cidx;
            dba[n] = db1[col];
#pragma unroll
            for (int s5 = 0; s5 < NS; ++s5) w2d[s5][n] = dw2[s5 * NDIR + col];
        }
#pragma unroll
        for (int mt = 0; mt < 2; ++mt) {
#pragma unroll
            for (int r = 0; r < 4; ++r) {
                float part[NS] = {0.f, 0.f, 0.f, 0.f, 0.f};
#pragma unroll
                for (int n = 0; n < 4; ++n) {
                    const float d = gelu_exact(acc[mt][n][r] + dba[n]);
#pragma unroll
                    for (int s5 = 0; s5 < NS; ++s5) part[s5] = fmaf(d, w2d[s5][n], part[s5]);
                }
#pragma unroll
                for (int o = 8; o > 0; o >>= 1)
#pragma unroll
                    for (int s5 = 0; s5 < NS; ++s5) part[s5] += __shfl_xor(part[s5], o, 64);
                if (cidx == 0) {
                    const size_t row = bm0 + wave * 32 + mt * 16 + (lane >> 4) * 4 + r;
#pragma unroll
                    for (int s5 = 0; s5 < NS; ++s5)
                        dpart_out[row * 20 + cb * NS + s5] = part[s5];
                }
            }
        }
    }
}

// ---------------- gates-lite: one thread per batch row ----------------
__device__ inline void softmax5(float* v) {
    float m = v[0];
#pragma unroll
    for (int s = 1; s < NS; ++s) m = fmaxf(m, v[s]);
    float sum = 0.f;
#pragma unroll
    for (int s = 0; s < NS; ++s) { v[s] = expf(v[s] - m); sum += v[s]; }
    const float inv = 1.f / sum;
#pragma unroll
    for (int s = 0; s < NS; ++s) v[s] *= inv;
}

__global__ __launch_bounds__(256) void htg_gates_lite(
    const float* __restrict__ np, const float* __restrict__ dpart,
    const float* __restrict__ lw1, const float* __restrict__ lb1,
    const float* __restrict__ lw2, const float* __restrict__ lb2,
    const float* __restrict__ db2, const float* __restrict__ cw,
    float* __restrict__ gates_out)
{
    const int b = blockIdx.x * 256 + threadIdx.x;  // 32x256 = 8192 exact
    float np0[NN], np1[NN];
#pragma unroll
    for (int n = 0; n < NN; ++n) {
        np0[n] = np[(size_t)b * NN + n];
        np1[n] = 1.f - np0[n];
    }
    float lp[8];
#pragma unroll
    for (int leaf = 0; leaf < 8; ++leaf) {
        const int c0 = (leaf >> 2) & 1, c1 = (leaf >> 1) & 1, c2 = leaf & 1;
        const float v0 = c0 ? np1[0] : np0[0];
        const float v1 = c1 ? np1[1 + c0] : np0[1 + c0];
        const float v2 = c2 ? np1[3 + 2 * c0 + c1] : np0[3 + 2 * c0 + c1];
        lp[leaf] = v0 * v1 * v2;
    }
    float t[10];
#pragma unroll
    for (int j = 0; j < 10; ++j) {
        float a = lb1[j];
#pragma unroll
        for (int leaf = 0; leaf < 8; ++leaf) a = fmaf(lp[leaf], lw1[j * 8 + leaf], a);
        t[j] = gelu_exact(a);
    }
    float tgt[NS];
#pragma unroll
    for (int s = 0; s < NS; ++s) {
        float a = lb2[s];
#pragma unroll
        for (int j = 0; j < 10; ++j) a = fmaf(t[j], lw2[s * 10 + j], a);
        tgt[s] = a;
    }
    softmax5(tgt);
    float dgt[NS];
#pragma unroll
    for (int s = 0; s < NS; ++s) {
        float a = db2[s];
#pragma unroll
        for (int cb = 0; cb < 4; ++cb) a += dpart[(size_t)b * 20 + cb * NS + s];
        dgt[s] = a;
    }
    softmax5(dgt);
    const float w = 1.f / (1.f + expf(-cw[0]));
    float g5[NS]; float sum = 0.f;
#pragma unroll
    for (int s = 0; s < NS; ++s) {
        g5[s] = fmaf(w, tgt[s] - dgt[s], dgt[s]);
        sum += g5[s];
    }
    const float inv = 1.f / sum;
#pragma unroll
    for (int s = 0; s < NS; ++s) gates_out[(size_t)b * NS + s] = g5[s] * inv;
}

// ---------------- combine: out[b][d] = sum_s gates[b][s] * logits[s][b][d] ----------------
__global__ __launch_bounds__(256) void htg_combine(
    const float* __restrict__ logits, const float* __restrict__ gates,
    float* __restrict__ out)
{
    const int b = blockIdx.x;
    float g[NS];
#pragma unroll
    for (int s = 0; s < NS; ++s) g[s] = gates[(size_t)b * NS + s];  // block-uniform
    const f32x4_t* lp = (const f32x4_t*)logits;
    f32x4_t* op = (f32x4_t*)out;
    const size_t rowbase = (size_t)b * (DCOL / 4);
#pragma unroll
    for (int u = 0; u < 4; ++u) {
        const size_t idx = rowbase + u * 256 + threadIdx.x;
        f32x4_t a = (f32x4_t)(0.f);
#pragma unroll
        for (int s = 0; s < NS; ++s) {
            const f32x4_t v = __builtin_nontemporal_load(&lp[(size_t)s * B_SZ * (DCOL / 4) + idx]);
            a.x = fmaf(g[s], v.x, a.x);
            a.y = fmaf(g[s], v.y, a.y);
            a.z = fmaf(g[s], v.z, a.z);
            a.w = fmaf(g[s], v.w, a.w);
        }
        __builtin_nontemporal_store(a, &op[idx]);
    }
}

extern "C" void kernel_launch(void* const* d_in, const int* in_sizes, int n_in,
                              void* d_out, int out_size, void* d_ws, size_t ws_size,
                              hipStream_t stream) {
    const float* features = (const float*)d_in[0];
    const float* logits   = (const float*)d_in[1];
    const float* tw1      = (const float*)d_in[2];
    const float* tb1      = (const float*)d_in[3];
    const float* tg       = (const float*)d_in[4];
    const float* tbn      = (const float*)d_in[5];
    const float* tw2      = (const float*)d_in[6];
    const float* tb2      = (const float*)d_in[7];
    const float* lw1      = (const float*)d_in[8];
    const float* lb1      = (const float*)d_in[9];
    const float* lw2      = (const float*)d_in[10];
    const float* lb2      = (const float*)d_in[11];
    const float* dw1      = (const float*)d_in[12];
    const float* db1      = (const float*)d_in[13];
    const float* dw2      = (const float*)d_in[14];
    const float* db2      = (const float*)d_in[15];
    const float* cw       = (const float*)d_in[16];

    float* out   = (float*)d_out;
    float* gates = out + (size_t)B_SZ * DCOL;  // tail of d_out (output 1)

    // scratch layout: Ah, Al [B*FEATN u16], Wh, Wl [NTOT*FEATN u16], np, dpart.
    const size_t nA = (size_t)B_SZ * FEATN;   // 8,388,608
    const size_t nW = (size_t)NTOT * FEATN;   //   720,896
    const size_t scratch_bytes = (2 * nA + 2 * nW) * sizeof(u16)
                               + (size_t)B_SZ * 27 * sizeof(float);  // ~37.3 MB
    // Prefer d_ws; fall back to front of d_out (~37MB < 134MB). Ordering safe:
    // convert -> gemm (reads conv bufs, writes np/dpart) -> gates_lite (reads
    // np/dpart, writes gates tail) -> combine (reads logits+gates only,
    // overwrites the scratch region last).
    char* scratch = (ws_size >= scratch_bytes) ? (char*)d_ws : (char*)d_out;
    u16* Ah = (u16*)scratch;
    u16* Al = Ah + nA;
    u16* Wh = Al + nA;
    u16* Wl = Wh + nW;
    float* np_buf    = (float*)(Wl + nW);
    float* dpart_buf = np_buf + (size_t)B_SZ * NN;

    htg_convert<<<2048, 256, 0, stream>>>(features, tw1, dw1, Ah, Al, Wh, Wl);

    dim3 gemm_grid(B_SZ / 128, NTOT / 64);  // 64 x 11
    htg_gemm_mfma<<<gemm_grid, 256, 0, stream>>>(Ah, Al, Wh, Wl,
                                                 tb1, tg, tbn, tw2, tb2,
                                                 db1, dw2, np_buf, dpart_buf);

    htg_gates_lite<<<B_SZ / 256, 256, 0, stream>>>(np_buf, dpart_buf,
                                                   lw1, lb1, lw2, lb2, db2, cw,
                                                   gates);

    htg_combine<<<B_SZ, 256, 0, stream>>>(logits, gates, out);
}